// Round 1
// baseline (375.699 us; speedup 1.0000x reference)
//
#include <hip/hip_runtime.h>
#include <math.h>

#define NN   100000   // nodes
#define NE   1600000  // edges
#define IND  256      // input dim
#define HIDD 64       // hidden dim
#define OUTD 40       // output dim
#define COEF 0.1f     // 2*mu/p = 2*0.1/2.0

#define PSHIFT 10
#define PSIZE  1024                       // nodes per partition
#define NPART  ((NN + PSIZE - 1) / PSIZE) // 98

#define CHUNK_A 4096      // edges per partition-pass block
#define PBLKS   ((NE + CHUNK_A - 1) / CHUNK_A)   // 391

typedef __attribute__((ext_vector_type(8))) short frag8;   // 8 bf16
typedef __attribute__((ext_vector_type(4))) float f32x4;

__device__ __forceinline__ unsigned short f2bf(float x) {  // RNE
    unsigned u = __float_as_uint(x);
    u += 0x7fffu + ((u >> 16) & 1u);
    return (unsigned short)(u >> 16);
}
__device__ __forceinline__ float bflo(unsigned v) { return __uint_as_float(v << 16); }
__device__ __forceinline__ float bfhi(unsigned v) { return __uint_as_float(v & 0xffff0000u); }

// ---- per-partition edge counts: LDS histogram, 98 global adds per block
__global__ __launch_bounds__(256) void pcount_kernel(const int* __restrict__ dst,
                                                     int* __restrict__ gcount) {
    __shared__ int cnt[NPART];
    int t = threadIdx.x;
    if (t < NPART) cnt[t] = 0;
    __syncthreads();
    int base = blockIdx.x * CHUNK_A;
#pragma unroll
    for (int j = 0; j < 16; j++) {
        int e = base + j * 256 + t;
        if (e < NE) atomicAdd(&cnt[dst[e] >> PSHIFT], 1);
    }
    __syncthreads();
    if (t < NPART) atomicAdd(&gcount[t], cnt[t]);
}

// ---- exclusive scan of 98 partition sums -> bscan (read-only) + gcursor (mutable)
// parallel LDS scan: 128 threads, removes the serial 98-dependent-load chain
__global__ __launch_bounds__(128) void pscan_kernel(const int* __restrict__ gcount,
                                                    int* __restrict__ bscan,
                                                    int* __restrict__ gcursor,
                                                    int* __restrict__ row_ptr) {
    __shared__ int s[128];
    int t = threadIdx.x;
    int v = (t < NPART) ? gcount[t] : 0;
    s[t] = v;
    __syncthreads();
    for (int off = 1; off < 128; off <<= 1) {
        int xv = (t >= off) ? s[t - off] : 0;
        __syncthreads();
        s[t] += xv;
        __syncthreads();
    }
    int excl = s[t] - v;
    if (t < NPART) {
        bscan[t]   = excl;
        gcursor[t] = excl;
    }
    if (t == NPART - 1) row_ptr[NN] = excl + v;   // == NE
}

// ---- bin edges by dst>>10 into partition-ordered ep (int2{src,dst})
__global__ __launch_bounds__(256) void pfill_kernel(const int* __restrict__ src,
                                                    const int* __restrict__ dst,
                                                    int* __restrict__ gcursor,
                                                    int2* __restrict__ ep) {
    __shared__ int cnt[NPART];
    __shared__ int basep[NPART];
    int t = threadIdx.x;
    if (t < NPART) cnt[t] = 0;
    __syncthreads();
    int base = blockIdx.x * CHUNK_A;

    int v[16];
#pragma unroll
    for (int j = 0; j < 16; j++) {
        int e = base + j * 256 + t;
        v[j] = (e < NE) ? dst[e] : -1;
        if (v[j] >= 0) atomicAdd(&cnt[v[j] >> PSHIFT], 1);
    }
    __syncthreads();
    if (t < NPART) {
        basep[t] = atomicAdd(&gcursor[t], cnt[t]);
        cnt[t] = 0;
    }
    __syncthreads();
#pragma unroll
    for (int j = 0; j < 16; j++) {
        int e = base + j * 256 + t;
        if (v[j] >= 0) {
            int p = v[j] >> PSHIFT;
            int pos = basep[p] + atomicAdd(&cnt[p], 1);
            ep[pos] = make_int2(src[e], v[j]);
        }
    }
}

// ---- per-partition: LDS degree histogram (replaces global deg_kernel),
// node quantities (fused nodeA), LDS scan -> row_ptr, LDS-cursor scatter.
// One 1024-thread block per partition; all global writes dense & CU-owned.
__global__ __launch_bounds__(1024) void fill3_kernel(const int* __restrict__ bscan,
                                                     const int2* __restrict__ ep,
                                                     int* __restrict__ row_ptr,
                                                     int* __restrict__ src_sorted,
                                                     float* __restrict__ dinv,
                                                     float* __restrict__ adinv,
                                                     float* __restrict__ beta) {
    __shared__ int cnt[PSIZE];
    __shared__ int scan[PSIZE];
    __shared__ int cursor[PSIZE];
    int p = blockIdx.x, t = threadIdx.x;
    int n0 = p * PSIZE;
    int n = n0 + t;

    cnt[t] = 0;
    __syncthreads();
    int ebase = bscan[p];
    int eend  = (p == NPART - 1) ? NE : bscan[p + 1];
    for (int e = ebase + t; e < eend; e += PSIZE)
        atomicAdd(&cnt[ep[e].y - n0], 1);
    __syncthreads();

    int d = cnt[t];
    if (n < NN) {
        float deg = (d > 0) ? (float)d : 1.0f;
        float di = rsqrtf(deg);
        dinv[n] = di;
        float denom = (float)d / deg + COEF;
        float a = 1.0f / denom;
        adinv[n] = a * di;
        beta[n]  = COEF * a;
    }

    scan[t] = d;
    __syncthreads();
    for (int off = 1; off < PSIZE; off <<= 1) {
        int x = (t >= off) ? scan[t - off] : 0;
        __syncthreads();
        scan[t] += x;
        __syncthreads();
    }
    int excl = scan[t] - d + ebase;
    if (n < NN) row_ptr[n] = excl;
    cursor[t] = excl;
    __syncthreads();

    for (int e = ebase + t; e < eend; e += PSIZE) {
        int2 sd = ep[e];
        int pos = atomicAdd(&cursor[sd.y - n0], 1);
        src_sorted[pos] = sd.x;
    }
}

// ---- one-shot: w1t[n][k] = bf16(W1[k][n])  (32 KB, L1-resident thereafter)
__global__ void w1t_kernel(const float* __restrict__ W1,
                           unsigned short* __restrict__ w1t) {
    int i = blockIdx.x * blockDim.x + threadIdx.x;
    if (i >= IND * HIDD) return;
    int k = i >> 6, n = i & 63;
    w1t[n * IND + k] = f2bf(W1[i]);
}

// ---------------------- h = relu(x @ W1 + b1), bf16 MFMA
// v2: LDS-staged A-tile. Coalesced row-major float4 loads (64 lanes = one
// contiguous 1KB row), bf16-convert into a 32KB swizzled LDS tile, then
// ds_read_b128 fragments. Swizzle byte^=((row&7)<<4) spreads the 16-lane
// same-column reads across all 32 banks (uniform 8 accesses/bank = b128 min).
__global__ __launch_bounds__(256) void gemm1_kernel(const float* __restrict__ x,
                                                    const unsigned short* __restrict__ w1t,
                                                    const float* __restrict__ b1,
                                                    unsigned short* __restrict__ hb) {
    __shared__ unsigned short xs[64 * IND];   // 64 rows x 256 bf16 = 32 KB (swizzled)
    int tid = threadIdx.x;
    int brow0 = blockIdx.x * 64;

    // ---- stage: 64 rows x 1KB fp32, fully coalesced
#pragma unroll
    for (int i = 0; i < 16; i++) {
        int idx = i * 256 + tid;        // 0..4095 over the 64x64 float4 grid
        int r   = idx >> 6;             // LDS row 0..63
        int c4  = idx & 63;             // float4 index within row
        int grow = brow0 + r;
        if (grow >= NN) grow = NN - 1;  // clamp; tail rows never stored
        float4 v = *(const float4*)(x + (size_t)grow * IND + c4 * 4);
        unsigned p0 = (unsigned)f2bf(v.x) | ((unsigned)f2bf(v.y) << 16);
        unsigned p1 = (unsigned)f2bf(v.z) | ((unsigned)f2bf(v.w) << 16);
        int byteInRow = c4 * 8;
        int off = r * 512 + (byteInRow ^ ((r & 7) << 4));
        uint2 pk; pk.x = p0; pk.y = p1;
        *(uint2*)((char*)xs + off) = pk;
    }
    __syncthreads();

    // ---- compute: per-wave 16x64 output tile
    int wave = tid >> 6, lane = tid & 63;
    int m = lane & 15, q = lane >> 4;
    int lrow = wave * 16 + m;
    const char* xrow = (const char*)xs + lrow * 512;
    int swz = (lrow & 7) << 4;

    f32x4 acc[4] = {};
#pragma unroll
    for (int ks = 0; ks < 8; ks++) {
        frag8 a = *(const frag8*)(xrow + ((ks * 64 + q * 16) ^ swz));
#pragma unroll
        for (int j = 0; j < 4; j++) {
            frag8 b = *(const frag8*)(w1t + (j * 16 + m) * IND + ks * 32 + q * 8);
            acc[j] = __builtin_amdgcn_mfma_f32_16x16x32_bf16(a, b, acc[j], 0, 0, 0);
        }
    }

    int row0 = brow0 + wave * 16;
#pragma unroll
    for (int j = 0; j < 4; j++) {
        int gcol = j * 16 + m;
        float bias = b1[gcol];
#pragma unroll
        for (int r = 0; r < 4; r++) {
            int grow = row0 + q * 4 + r;
            if (grow < NN)
                hb[(size_t)grow * HIDD + gcol] = f2bf(fmaxf(acc[j][r] + bias, 0.0f));
        }
    }
}

// --- fn[i] = beta[i]*h[i] + adinv[i] * sum_e dinv[src_e] * f[src_e]  (bf16 CSR gather)
__global__ __launch_bounds__(256) void gather_kernel(const int* __restrict__ row_ptr,
                                                     const int* __restrict__ src_sorted,
                                                     const float* __restrict__ dinv,
                                                     const float* __restrict__ adinv,
                                                     const unsigned short* __restrict__ fb,
                                                     const unsigned short* __restrict__ hb,
                                                     const float* __restrict__ beta,
                                                     unsigned short* __restrict__ fnb) {
    int wid = threadIdx.x >> 6, lane = threadIdx.x & 63;
    int node = blockIdx.x * 4 + wid;
    if (node >= NN) return;
    int base = row_ptr[node];
    int end  = row_ptr[node + 1];
    int g = lane >> 3, c = lane & 7;

    float acc[8];
#pragma unroll
    for (int i = 0; i < 8; i++) acc[i] = 0.f;

    for (int e = base + g; e < end; e += 8) {
        int s   = src_sorted[e];
        float w = dinv[s];
        uint4 v = ((const uint4*)fb)[(size_t)s * 8 + c];
        acc[0] += w * bflo(v.x); acc[1] += w * bfhi(v.x);
        acc[2] += w * bflo(v.y); acc[3] += w * bfhi(v.y);
        acc[4] += w * bflo(v.z); acc[5] += w * bfhi(v.z);
        acc[6] += w * bflo(v.w); acc[7] += w * bfhi(v.w);
    }
#pragma unroll
    for (int i = 0; i < 8; i++) {
        acc[i] += __shfl_xor(acc[i], 8);
        acc[i] += __shfl_xor(acc[i], 16);
        acc[i] += __shfl_xor(acc[i], 32);
    }

    if (g == 0) {
        float an = adinv[node];
        float b  = beta[node];
        uint4 hv = ((const uint4*)hb)[(size_t)node * 8 + c];
        float o[8];
        o[0] = an * acc[0] + b * bflo(hv.x); o[1] = an * acc[1] + b * bfhi(hv.x);
        o[2] = an * acc[2] + b * bflo(hv.y); o[3] = an * acc[3] + b * bfhi(hv.y);
        o[4] = an * acc[4] + b * bflo(hv.z); o[5] = an * acc[5] + b * bfhi(hv.z);
        o[6] = an * acc[6] + b * bflo(hv.w); o[7] = an * acc[7] + b * bfhi(hv.w);
        uint4 r;
        r.x = (unsigned)f2bf(o[0]) | ((unsigned)f2bf(o[1]) << 16);
        r.y = (unsigned)f2bf(o[2]) | ((unsigned)f2bf(o[3]) << 16);
        r.z = (unsigned)f2bf(o[4]) | ((unsigned)f2bf(o[5]) << 16);
        r.w = (unsigned)f2bf(o[6]) | ((unsigned)f2bf(o[7]) << 16);
        ((uint4*)fnb)[(size_t)node * 8 + c] = r;
    }
}

// ------------------- out = log_softmax(f @ W2 + b2), bf16 MFMA
__global__ __launch_bounds__(256) void out_kernel(const unsigned short* __restrict__ fb,
                                                  const float* __restrict__ W2,
                                                  const float* __restrict__ b2,
                                                  float* __restrict__ out) {
    __shared__ float w2l[HIDD * OUTD];   // raw W2, 10 KB
    int tid = threadIdx.x;
    for (int i = tid; i < HIDD * OUTD; i += 256) w2l[i] = W2[i];
    __syncthreads();

    int wave = tid >> 6, lane = tid & 63;
    int m = lane & 15, q = lane >> 4;

    frag8 bfr[3][2];
    float bias[3];
#pragma unroll
    for (int j = 0; j < 3; j++) {
        int n = j * 16 + m;
        bias[j] = (n < OUTD) ? b2[n] : 0.0f;
#pragma unroll
        for (int s = 0; s < 2; s++) {
            short tmp[8];
#pragma unroll
            for (int i = 0; i < 8; i++) {
                int k = s * 32 + q * 8 + i;
                float w = (n < OUTD) ? w2l[k * OUTD + n] : 0.0f;
                tmp[i] = (short)f2bf(w);
            }
            bfr[j][s] = *(frag8*)tmp;
        }
    }

    int block0 = blockIdx.x * 256;
    for (int t = 0; t < 4; t++) {
        int row0 = block0 + wave * 64 + t * 16;
        if (row0 >= NN) break;
        int arow = row0 + m;
        if (arow >= NN) arow = NN - 1;
        const frag8* ap = (const frag8*)(fb + (size_t)arow * HIDD);
        frag8 a0 = ap[q];
        frag8 a1 = ap[4 + q];

        f32x4 acc[3] = {};
#pragma unroll
        for (int j = 0; j < 3; j++) {
            acc[j] = __builtin_amdgcn_mfma_f32_16x16x32_bf16(a0, bfr[j][0], acc[j], 0, 0, 0);
            acc[j] = __builtin_amdgcn_mfma_f32_16x16x32_bf16(a1, bfr[j][1], acc[j], 0, 0, 0);
        }

#pragma unroll
        for (int r = 0; r < 4; r++) {
            int orow = row0 + q * 4 + r;
            float v0 = acc[0][r] + bias[0];
            float v1 = acc[1][r] + bias[1];
            float v2 = (m < 8) ? (acc[2][r] + bias[2]) : -INFINITY;
            float mx = fmaxf(fmaxf(v0, v1), v2);
            mx = fmaxf(mx, __shfl_xor(mx, 1));
            mx = fmaxf(mx, __shfl_xor(mx, 2));
            mx = fmaxf(mx, __shfl_xor(mx, 4));
            mx = fmaxf(mx, __shfl_xor(mx, 8));
            float sum = __expf(v0 - mx) + __expf(v1 - mx) + ((m < 8) ? __expf(v2 - mx) : 0.0f);
            sum += __shfl_xor(sum, 1);
            sum += __shfl_xor(sum, 2);
            sum += __shfl_xor(sum, 4);
            sum += __shfl_xor(sum, 8);
            float ls = mx + __logf(sum);
            if (orow < NN) {
                float* orow_p = out + (size_t)orow * OUTD;
                orow_p[m]      = v0 - ls;
                orow_p[16 + m] = v1 - ls;
                if (m < 8) orow_p[32 + m] = v2 - ls;
            }
        }
    }
}

// ----------------------------------------------------------------------------
static inline size_t align256(size_t x) { return (x + 255) & ~(size_t)255; }

extern "C" void kernel_launch(void* const* d_in, const int* in_sizes, int n_in,
                              void* d_out, int out_size, void* d_ws, size_t ws_size,
                              hipStream_t stream) {
    const float* x  = (const float*)d_in[0];
    const int*   ei = (const int*)d_in[1];
    const float* W1 = (const float*)d_in[2];
    const float* b1 = (const float*)d_in[3];
    const float* W2 = (const float*)d_in[4];
    const float* b2 = (const float*)d_in[5];
    float* out = (float*)d_out;

    const int* src = ei;        // edge_index[0]
    const int* dst = ei + NE;   // edge_index[1]

    char* ws = (char*)d_ws;
    size_t off = 0;
    float* dinv     = (float*)(ws + off); off += align256((size_t)NN * 4);
    float* adinv    = (float*)(ws + off); off += align256((size_t)NN * 4);
    float* beta     = (float*)(ws + off); off += align256((size_t)NN * 4);
    int*   row_ptr  = (int*)(ws + off);   off += align256((size_t)(NN + 1) * 4);
    int*   gcount   = (int*)(ws + off);   off += align256((size_t)NPART * 4);
    int*   bscan    = (int*)(ws + off);   off += align256((size_t)NPART * 4);
    int*   gcursor  = (int*)(ws + off);   off += align256((size_t)NPART * 4);
    int*   src_sorted = (int*)(ws + off); off += align256((size_t)NE * 4);
    int2*  ep       = (int2*)(ws + off);  off += align256((size_t)NE * 8);
    unsigned short* w1t = (unsigned short*)(ws + off); off += align256((size_t)IND * HIDD * 2);
    unsigned short* hb = (unsigned short*)(ws + off); off += align256((size_t)NN * HIDD * 2);
    unsigned short* fa = (unsigned short*)(ws + off); off += align256((size_t)NN * HIDD * 2);
    unsigned short* fb = (unsigned short*)(ws + off); off += align256((size_t)NN * HIDD * 2);

    hipMemsetAsync(gcount, 0, (size_t)NPART * 4, stream);

    pcount_kernel<<<PBLKS, 256, 0, stream>>>(dst, gcount);
    pscan_kernel<<<1, 128, 0, stream>>>(gcount, bscan, gcursor, row_ptr);
    pfill_kernel<<<PBLKS, 256, 0, stream>>>(src, dst, gcursor, ep);
    fill3_kernel<<<NPART, 1024, 0, stream>>>(bscan, ep, row_ptr, src_sorted,
                                             dinv, adinv, beta);

    w1t_kernel<<<(IND * HIDD + 255) / 256, 256, 0, stream>>>(W1, w1t);
    gemm1_kernel<<<(NN + 63) / 64, 256, 0, stream>>>(x, w1t, b1, hb);

    // iteration 1: fa = beta*h + A h
    gather_kernel<<<(NN + 3) / 4, 256, 0, stream>>>(row_ptr, src_sorted, dinv, adinv,
                                                    hb, hb, beta, fa);
    // iteration 2: fb = beta*h + A fa
    gather_kernel<<<(NN + 3) / 4, 256, 0, stream>>>(row_ptr, src_sorted, dinv, adinv,
                                                    fa, hb, beta, fb);

    out_kernel<<<(NN + 255) / 256, 256, 0, stream>>>(fb, W2, b2, out);
}

// Round 2
// 355.873 us; speedup vs baseline: 1.0557x; 1.0557x over previous
//
#include <hip/hip_runtime.h>
#include <math.h>

#define NN   100000   // nodes
#define NE   1600000  // edges
#define IND  256      // input dim
#define HIDD 64       // hidden dim
#define OUTD 40       // output dim
#define COEF 0.1f     // 2*mu/p = 2*0.1/2.0

#define PSHIFT 10
#define PSIZE  1024                       // nodes per partition
#define NPART  ((NN + PSIZE - 1) / PSIZE) // 98

#define CHUNK_A 4096      // edges per partition-pass block
#define PBLKS   ((NE + CHUNK_A - 1) / CHUNK_A)   // 391

#define G1_TILES ((NN + 63) / 64)   // 1563 64-row tiles
#define G1_BLOCKS 512               // 2 per CU (64 KB LDS each)

typedef __attribute__((ext_vector_type(8))) short frag8;   // 8 bf16
typedef __attribute__((ext_vector_type(4))) float f32x4;

__device__ __forceinline__ unsigned short f2bf(float x) {  // RNE
    unsigned u = __float_as_uint(x);
    u += 0x7fffu + ((u >> 16) & 1u);
    return (unsigned short)(u >> 16);
}
__device__ __forceinline__ float bflo(unsigned v) { return __uint_as_float(v << 16); }
__device__ __forceinline__ float bfhi(unsigned v) { return __uint_as_float(v & 0xffff0000u); }

// ---- per-partition edge counts: LDS histogram, 98 global adds per block
__global__ __launch_bounds__(256) void pcount_kernel(const int* __restrict__ dst,
                                                     int* __restrict__ gcount) {
    __shared__ int cnt[NPART];
    int t = threadIdx.x;
    if (t < NPART) cnt[t] = 0;
    __syncthreads();
    int base = blockIdx.x * CHUNK_A;
#pragma unroll
    for (int j = 0; j < 16; j++) {
        int e = base + j * 256 + t;
        if (e < NE) atomicAdd(&cnt[dst[e] >> PSHIFT], 1);
    }
    __syncthreads();
    if (t < NPART) atomicAdd(&gcount[t], cnt[t]);
}

// ---- exclusive scan of 98 partition sums -> bscan (read-only) + gcursor (mutable)
__global__ __launch_bounds__(128) void pscan_kernel(const int* __restrict__ gcount,
                                                    int* __restrict__ bscan,
                                                    int* __restrict__ gcursor,
                                                    int* __restrict__ row_ptr) {
    __shared__ int s[128];
    int t = threadIdx.x;
    int v = (t < NPART) ? gcount[t] : 0;
    s[t] = v;
    __syncthreads();
    for (int off = 1; off < 128; off <<= 1) {
        int xv = (t >= off) ? s[t - off] : 0;
        __syncthreads();
        s[t] += xv;
        __syncthreads();
    }
    int excl = s[t] - v;
    if (t < NPART) {
        bscan[t]   = excl;
        gcursor[t] = excl;
    }
    if (t == NPART - 1) row_ptr[NN] = excl + v;   // == NE
}

// ---- bin edges by dst>>10 into partition-ordered ep (int2{src,dst})
__global__ __launch_bounds__(256) void pfill_kernel(const int* __restrict__ src,
                                                    const int* __restrict__ dst,
                                                    int* __restrict__ gcursor,
                                                    int2* __restrict__ ep) {
    __shared__ int cnt[NPART];
    __shared__ int basep[NPART];
    int t = threadIdx.x;
    if (t < NPART) cnt[t] = 0;
    __syncthreads();
    int base = blockIdx.x * CHUNK_A;

    int v[16];
#pragma unroll
    for (int j = 0; j < 16; j++) {
        int e = base + j * 256 + t;
        v[j] = (e < NE) ? dst[e] : -1;
        if (v[j] >= 0) atomicAdd(&cnt[v[j] >> PSHIFT], 1);
    }
    __syncthreads();
    if (t < NPART) {
        basep[t] = atomicAdd(&gcursor[t], cnt[t]);
        cnt[t] = 0;
    }
    __syncthreads();
#pragma unroll
    for (int j = 0; j < 16; j++) {
        int e = base + j * 256 + t;
        if (v[j] >= 0) {
            int p = v[j] >> PSHIFT;
            int pos = basep[p] + atomicAdd(&cnt[p], 1);
            ep[pos] = make_int2(src[e], v[j]);
        }
    }
}

// ---- per-partition: LDS degree histogram, node quantities, LDS scan -> row_ptr,
// LDS-cursor scatter. One 1024-thread block per partition.
__global__ __launch_bounds__(1024) void fill3_kernel(const int* __restrict__ bscan,
                                                     const int2* __restrict__ ep,
                                                     int* __restrict__ row_ptr,
                                                     int* __restrict__ src_sorted,
                                                     float* __restrict__ dinv,
                                                     float* __restrict__ adinv,
                                                     float* __restrict__ beta) {
    __shared__ int cnt[PSIZE];
    __shared__ int scan[PSIZE];
    __shared__ int cursor[PSIZE];
    int p = blockIdx.x, t = threadIdx.x;
    int n0 = p * PSIZE;
    int n = n0 + t;

    cnt[t] = 0;
    __syncthreads();
    int ebase = bscan[p];
    int eend  = (p == NPART - 1) ? NE : bscan[p + 1];
    for (int e = ebase + t; e < eend; e += PSIZE)
        atomicAdd(&cnt[ep[e].y - n0], 1);
    __syncthreads();

    int d = cnt[t];
    if (n < NN) {
        float deg = (d > 0) ? (float)d : 1.0f;
        float di = rsqrtf(deg);
        dinv[n] = di;
        float denom = (float)d / deg + COEF;
        float a = 1.0f / denom;
        adinv[n] = a * di;
        beta[n]  = COEF * a;
    }

    scan[t] = d;
    __syncthreads();
    for (int off = 1; off < PSIZE; off <<= 1) {
        int x = (t >= off) ? scan[t - off] : 0;
        __syncthreads();
        scan[t] += x;
        __syncthreads();
    }
    int excl = scan[t] - d + ebase;
    if (n < NN) row_ptr[n] = excl;
    cursor[t] = excl;
    __syncthreads();

    for (int e = ebase + t; e < eend; e += PSIZE) {
        int2 sd = ep[e];
        int pos = atomicAdd(&cursor[sd.y - n0], 1);
        src_sorted[pos] = sd.x;
    }
}

// ---- one-shot: w1t[n][k] = bf16(W1[k][n])  (32 KB, L1-resident thereafter)
__global__ void w1t_kernel(const float* __restrict__ W1,
                           unsigned short* __restrict__ w1t) {
    int i = blockIdx.x * blockDim.x + threadIdx.x;
    if (i >= IND * HIDD) return;
    int k = i >> 6, n = i & 63;
    w1t[n * IND + k] = f2bf(W1[i]);
}

// ---------------------- h = relu(x @ W1 + b1), bf16 MFMA
// v3: persistent blocks, double-buffered LDS, one-tile-ahead register prefetch.
// Per iter: convert+ds_write tile t -> issue tile t+1 loads -> barrier ->
// MFMA compute tile t. 16 float4 (16 KB/wave) kept in flight across the
// compute phase (launch_bounds(256,2) lifts VGPR cap); latency hidden by ILP.
__global__ __launch_bounds__(256, 2) void gemm1_kernel(const float* __restrict__ x,
                                                       const unsigned short* __restrict__ w1t,
                                                       const float* __restrict__ b1,
                                                       unsigned short* __restrict__ hb) {
    __shared__ unsigned short xs[2][64 * IND];   // 2 x 32 KB, swizzled
    int tid = threadIdx.x;
    int wave = tid >> 6, lane = tid & 63;
    int m = lane & 15, q = lane >> 4;

    // epilogue constants (hoisted)
    float bias[4];
#pragma unroll
    for (int j = 0; j < 4; j++) bias[j] = b1[j * 16 + m];

    // compute-phase LDS addressing (row = wave*16+m)
    int lrow = wave * 16 + m;
    const char* xrow0 = (const char*)xs[0] + lrow * 512;
    const char* xrow1 = (const char*)xs[1] + lrow * 512;
    int swz = (lrow & 7) << 4;

    // staging: iteration i covers row i*4+wave, float4 col = lane (coalesced 1KB/row)
    float4 v[16];
    int t = blockIdx.x;

#pragma unroll
    for (int i = 0; i < 16; i++) {
        int grow = t * 64 + i * 4 + wave;
        if (grow >= NN) grow = NN - 1;
        v[i] = *(const float4*)(x + (size_t)grow * IND + lane * 4);
    }

    int buf = 0;
    for (; t < G1_TILES; t += G1_BLOCKS) {
        // ---- convert + swizzled ds_write of tile t
        unsigned short* xb = xs[buf];
#pragma unroll
        for (int i = 0; i < 16; i++) {
            int rr = i * 4 + wave;
            unsigned p0 = (unsigned)f2bf(v[i].x) | ((unsigned)f2bf(v[i].y) << 16);
            unsigned p1 = (unsigned)f2bf(v[i].z) | ((unsigned)f2bf(v[i].w) << 16);
            uint2 pk; pk.x = p0; pk.y = p1;
            int off = rr * 512 + ((lane * 8) ^ ((rr & 7) << 4));
            *(uint2*)((char*)xb + off) = pk;
        }

        // ---- issue next tile's loads (stay in flight across barrier+compute)
        int tn = t + G1_BLOCKS;
        if (tn < G1_TILES) {
#pragma unroll
            for (int i = 0; i < 16; i++) {
                int grow = tn * 64 + i * 4 + wave;
                if (grow >= NN) grow = NN - 1;
                v[i] = *(const float4*)(x + (size_t)grow * IND + lane * 4);
            }
        }

        __syncthreads();

        // ---- MFMA compute of tile t
        const char* xrow = buf ? xrow1 : xrow0;
        f32x4 acc[4] = {};
#pragma unroll
        for (int ks = 0; ks < 8; ks++) {
            frag8 a = *(const frag8*)(xrow + ((ks * 64 + q * 16) ^ swz));
#pragma unroll
            for (int j = 0; j < 4; j++) {
                frag8 b = *(const frag8*)(w1t + (j * 16 + m) * IND + ks * 32 + q * 8);
                acc[j] = __builtin_amdgcn_mfma_f32_16x16x32_bf16(a, b, acc[j], 0, 0, 0);
            }
        }

        int row0 = t * 64 + wave * 16;
#pragma unroll
        for (int j = 0; j < 4; j++) {
            int gcol = j * 16 + m;
#pragma unroll
            for (int r = 0; r < 4; r++) {
                int grow = row0 + q * 4 + r;
                if (grow < NN)
                    hb[(size_t)grow * HIDD + gcol] = f2bf(fmaxf(acc[j][r] + bias[j], 0.0f));
            }
        }
        buf ^= 1;
        // single barrier per iter is sufficient: buffer written at iter k+2 is
        // separated from its read at iter k by the barrier at k+1.
    }
}

// --- fn[i] = beta[i]*h[i] + adinv[i] * sum_e dinv[src_e] * f[src_e]  (bf16 CSR gather)
__global__ __launch_bounds__(256) void gather_kernel(const int* __restrict__ row_ptr,
                                                     const int* __restrict__ src_sorted,
                                                     const float* __restrict__ dinv,
                                                     const float* __restrict__ adinv,
                                                     const unsigned short* __restrict__ fb,
                                                     const unsigned short* __restrict__ hb,
                                                     const float* __restrict__ beta,
                                                     unsigned short* __restrict__ fnb) {
    int wid = threadIdx.x >> 6, lane = threadIdx.x & 63;
    int node = blockIdx.x * 4 + wid;
    if (node >= NN) return;
    int base = row_ptr[node];
    int end  = row_ptr[node + 1];
    int g = lane >> 3, c = lane & 7;

    float acc[8];
#pragma unroll
    for (int i = 0; i < 8; i++) acc[i] = 0.f;

    for (int e = base + g; e < end; e += 8) {
        int s   = src_sorted[e];
        float w = dinv[s];
        uint4 v = ((const uint4*)fb)[(size_t)s * 8 + c];
        acc[0] += w * bflo(v.x); acc[1] += w * bfhi(v.x);
        acc[2] += w * bflo(v.y); acc[3] += w * bfhi(v.y);
        acc[4] += w * bflo(v.z); acc[5] += w * bfhi(v.z);
        acc[6] += w * bflo(v.w); acc[7] += w * bfhi(v.w);
    }
#pragma unroll
    for (int i = 0; i < 8; i++) {
        acc[i] += __shfl_xor(acc[i], 8);
        acc[i] += __shfl_xor(acc[i], 16);
        acc[i] += __shfl_xor(acc[i], 32);
    }

    if (g == 0) {
        float an = adinv[node];
        float b  = beta[node];
        uint4 hv = ((const uint4*)hb)[(size_t)node * 8 + c];
        float o[8];
        o[0] = an * acc[0] + b * bflo(hv.x); o[1] = an * acc[1] + b * bfhi(hv.x);
        o[2] = an * acc[2] + b * bflo(hv.y); o[3] = an * acc[3] + b * bfhi(hv.y);
        o[4] = an * acc[4] + b * bflo(hv.z); o[5] = an * acc[5] + b * bfhi(hv.z);
        o[6] = an * acc[6] + b * bflo(hv.w); o[7] = an * acc[7] + b * bfhi(hv.w);
        uint4 r;
        r.x = (unsigned)f2bf(o[0]) | ((unsigned)f2bf(o[1]) << 16);
        r.y = (unsigned)f2bf(o[2]) | ((unsigned)f2bf(o[3]) << 16);
        r.z = (unsigned)f2bf(o[4]) | ((unsigned)f2bf(o[5]) << 16);
        r.w = (unsigned)f2bf(o[6]) | ((unsigned)f2bf(o[7]) << 16);
        ((uint4*)fnb)[(size_t)node * 8 + c] = r;
    }
}

// ------------------- out = log_softmax(f @ W2 + b2), bf16 MFMA
__global__ __launch_bounds__(256) void out_kernel(const unsigned short* __restrict__ fb,
                                                  const float* __restrict__ W2,
                                                  const float* __restrict__ b2,
                                                  float* __restrict__ out) {
    __shared__ float w2l[HIDD * OUTD];   // raw W2, 10 KB
    int tid = threadIdx.x;
    for (int i = tid; i < HIDD * OUTD; i += 256) w2l[i] = W2[i];
    __syncthreads();

    int wave = tid >> 6, lane = tid & 63;
    int m = lane & 15, q = lane >> 4;

    frag8 bfr[3][2];
    float bias[3];
#pragma unroll
    for (int j = 0; j < 3; j++) {
        int n = j * 16 + m;
        bias[j] = (n < OUTD) ? b2[n] : 0.0f;
#pragma unroll
        for (int s = 0; s < 2; s++) {
            short tmp[8];
#pragma unroll
            for (int i = 0; i < 8; i++) {
                int k = s * 32 + q * 8 + i;
                float w = (n < OUTD) ? w2l[k * OUTD + n] : 0.0f;
                tmp[i] = (short)f2bf(w);
            }
            bfr[j][s] = *(frag8*)tmp;
        }
    }

    int block0 = blockIdx.x * 256;
    for (int t = 0; t < 4; t++) {
        int row0 = block0 + wave * 64 + t * 16;
        if (row0 >= NN) break;
        int arow = row0 + m;
        if (arow >= NN) arow = NN - 1;
        const frag8* ap = (const frag8*)(fb + (size_t)arow * HIDD);
        frag8 a0 = ap[q];
        frag8 a1 = ap[4 + q];

        f32x4 acc[3] = {};
#pragma unroll
        for (int j = 0; j < 3; j++) {
            acc[j] = __builtin_amdgcn_mfma_f32_16x16x32_bf16(a0, bfr[j][0], acc[j], 0, 0, 0);
            acc[j] = __builtin_amdgcn_mfma_f32_16x16x32_bf16(a1, bfr[j][1], acc[j], 0, 0, 0);
        }

#pragma unroll
        for (int r = 0; r < 4; r++) {
            int orow = row0 + q * 4 + r;
            float v0 = acc[0][r] + bias[0];
            float v1 = acc[1][r] + bias[1];
            float v2 = (m < 8) ? (acc[2][r] + bias[2]) : -INFINITY;
            float mx = fmaxf(fmaxf(v0, v1), v2);
            mx = fmaxf(mx, __shfl_xor(mx, 1));
            mx = fmaxf(mx, __shfl_xor(mx, 2));
            mx = fmaxf(mx, __shfl_xor(mx, 4));
            mx = fmaxf(mx, __shfl_xor(mx, 8));
            float sum = __expf(v0 - mx) + __expf(v1 - mx) + ((m < 8) ? __expf(v2 - mx) : 0.0f);
            sum += __shfl_xor(sum, 1);
            sum += __shfl_xor(sum, 2);
            sum += __shfl_xor(sum, 4);
            sum += __shfl_xor(sum, 8);
            float ls = mx + __logf(sum);
            if (orow < NN) {
                float* orow_p = out + (size_t)orow * OUTD;
                orow_p[m]      = v0 - ls;
                orow_p[16 + m] = v1 - ls;
                if (m < 8) orow_p[32 + m] = v2 - ls;
            }
        }
    }
}

// ----------------------------------------------------------------------------
static inline size_t align256(size_t x) { return (x + 255) & ~(size_t)255; }

extern "C" void kernel_launch(void* const* d_in, const int* in_sizes, int n_in,
                              void* d_out, int out_size, void* d_ws, size_t ws_size,
                              hipStream_t stream) {
    const float* x  = (const float*)d_in[0];
    const int*   ei = (const int*)d_in[1];
    const float* W1 = (const float*)d_in[2];
    const float* b1 = (const float*)d_in[3];
    const float* W2 = (const float*)d_in[4];
    const float* b2 = (const float*)d_in[5];
    float* out = (float*)d_out;

    const int* src = ei;        // edge_index[0]
    const int* dst = ei + NE;   // edge_index[1]

    char* ws = (char*)d_ws;
    size_t off = 0;
    float* dinv     = (float*)(ws + off); off += align256((size_t)NN * 4);
    float* adinv    = (float*)(ws + off); off += align256((size_t)NN * 4);
    float* beta     = (float*)(ws + off); off += align256((size_t)NN * 4);
    int*   row_ptr  = (int*)(ws + off);   off += align256((size_t)(NN + 1) * 4);
    int*   gcount   = (int*)(ws + off);   off += align256((size_t)NPART * 4);
    int*   bscan    = (int*)(ws + off);   off += align256((size_t)NPART * 4);
    int*   gcursor  = (int*)(ws + off);   off += align256((size_t)NPART * 4);
    int*   src_sorted = (int*)(ws + off); off += align256((size_t)NE * 4);
    int2*  ep       = (int2*)(ws + off);  off += align256((size_t)NE * 8);
    unsigned short* w1t = (unsigned short*)(ws + off); off += align256((size_t)IND * HIDD * 2);
    unsigned short* hb = (unsigned short*)(ws + off); off += align256((size_t)NN * HIDD * 2);
    unsigned short* fa = (unsigned short*)(ws + off); off += align256((size_t)NN * HIDD * 2);
    unsigned short* fb = (unsigned short*)(ws + off); off += align256((size_t)NN * HIDD * 2);

    hipMemsetAsync(gcount, 0, (size_t)NPART * 4, stream);

    pcount_kernel<<<PBLKS, 256, 0, stream>>>(dst, gcount);
    pscan_kernel<<<1, 128, 0, stream>>>(gcount, bscan, gcursor, row_ptr);
    pfill_kernel<<<PBLKS, 256, 0, stream>>>(src, dst, gcursor, ep);
    fill3_kernel<<<NPART, 1024, 0, stream>>>(bscan, ep, row_ptr, src_sorted,
                                             dinv, adinv, beta);

    w1t_kernel<<<(IND * HIDD + 255) / 256, 256, 0, stream>>>(W1, w1t);
    gemm1_kernel<<<G1_BLOCKS, 256, 0, stream>>>(x, w1t, b1, hb);

    // iteration 1: fa = beta*h + A h
    gather_kernel<<<(NN + 3) / 4, 256, 0, stream>>>(row_ptr, src_sorted, dinv, adinv,
                                                    hb, hb, beta, fa);
    // iteration 2: fb = beta*h + A fa
    gather_kernel<<<(NN + 3) / 4, 256, 0, stream>>>(row_ptr, src_sorted, dinv, adinv,
                                                    fa, hb, beta, fb);

    out_kernel<<<(NN + 255) / 256, 256, 0, stream>>>(fb, W2, b2, out);
}